// Round 4
// baseline (109.636 us; speedup 1.0000x reference)
//
#include <hip/hip_runtime.h>

// Loss_net: neural-ODE loss forward. R=8192 samples, D=3, N=10 RK4 super-steps.
// 16 lanes per sample: 2 active hat-basis indices {k,k+1} x 4 (l in {0,1,2}, l==3 idle)
// x 2 hidden-halves (h {0,1,2} / {3,4}+pad). All lanes run a uniform 3-unit stream
// with zero weights on idle/pad lanes. Cross-lane sums via DPP butterflies (VALU pipe).
// 131072 threads = 2048 waves = 2 waves/SIMD chip-wide (fills dependent-chain stalls).

#define R_    8192
#define M_    10
#define L_    3
#define HID_  5
#define D_    3
#define N_    10
#define H_    0.1f
#define LOG_2PI 1.8378770664093453f
#define NWAVES 2048   // 512 blocks x 256 threads / 64

__device__ __forceinline__ float fast_tanh(float x) {
    // tanh(x) = 1 - 2/(exp(2x)+1); exp via hw exp2, rcp via hw rcp (~1e-7 rel err)
    float e = __builtin_amdgcn_exp2f(x * 2.8853900817779268f); // 2*log2(e)*x
    return fmaf(-2.0f, __builtin_amdgcn_rcpf(e + 1.0f), 1.0f);
}

// --- DPP butterfly add over 16 contiguous lanes (all lanes get the sum) ---
// 0xB1 quad_perm xor1, 0x4E quad_perm xor2, 0x141 row_half_mirror (i<->7-i in 8),
// 0x140 row_mirror (i<->15-i in 16). NOTE: 0x142 is ROW_BCAST15, not a mirror.
template<int CTRL>
__device__ __forceinline__ float dpp_addf(float v) {
    int t = __builtin_amdgcn_update_dpp(0, __float_as_int(v), CTRL, 0xF, 0xF, true);
    return v + __int_as_float(t);
}
__device__ __forceinline__ float red16(float v) {
    v = dpp_addf<0xB1>(v);
    v = dpp_addf<0x4E>(v);
    v = dpp_addf<0x141>(v);
    v = dpp_addf<0x140>(v);
    return v;
}

struct BlkW {
    float w1[3][D_];   // my 3 hidden units (pad unit = 0)
    float b1v[3];
    float w2[D_][3];
    float b2v[D_];     // only (act && hh==0) lane holds real b2
    float g[3];        // g[u] = sum_d w2[d][u]*w1[u][d]
};

__device__ __forceinline__ void load_blk(BlkW& B,
                                         const float* __restrict__ W1,
                                         const float* __restrict__ b1,
                                         const float* __restrict__ W2,
                                         const float* __restrict__ b2,
                                         int i, int l, int hh, bool act) {
    int blk = act ? (i * L_ + l) : 0;           // clamp so loads stay in-bounds
    #pragma unroll
    for (int u = 0; u < 3; ++u) {
        int h  = hh * 3 + u;
        bool au = act && (h < HID_);
        int hs = (h < HID_) ? h : 0;            // safe index for pad unit
        #pragma unroll
        for (int d = 0; d < D_; ++d) {
            float w1v = W1[blk * HID_ * D_ + hs * D_ + d];
            B.w1[u][d] = au ? w1v : 0.0f;
            float w2v = W2[blk * D_ * HID_ + d * HID_ + hs];
            B.w2[d][u] = au ? w2v : 0.0f;
        }
        float b1x = b1[blk * HID_ + hs];
        B.b1v[u] = au ? b1x : 0.0f;
    }
    bool ab2 = act && (hh == 0);
    #pragma unroll
    for (int d = 0; d < D_; ++d) {
        float b2x = b2[blk * D_ + d];
        B.b2v[d] = ab2 ? b2x : 0.0f;
    }
    #pragma unroll
    for (int u = 0; u < 3; ++u)
        B.g[u] = B.w2[0][u] * B.w1[u][0] + B.w2[1][u] * B.w1[u][1] + B.w2[2][u] * B.w1[u][2];
}

// v field eval: lane computes its 3-unit partial, then 16-lane DPP reduce.
// All 16 lanes end with the full v vector.
__device__ __forceinline__ void v_eval(const BlkW& B, float kf, int ii, float t,
                                       float x0, float x1, float x2,
                                       float& v0, float& v1, float& v2) {
    float w = fmaf(t, 10.0f, -kf);          // u - k
    float p = ii ? w : (1.0f - w);          // my basis weight
    float a[3];
    #pragma unroll
    for (int u = 0; u < 3; ++u) {
        float pre = fmaf(B.w1[u][0], x0, fmaf(B.w1[u][1], x1, fmaf(B.w1[u][2], x2, B.b1v[u])));
        a[u] = fast_tanh(pre);
    }
    float y0 = B.b2v[0], y1 = B.b2v[1], y2 = B.b2v[2];
    #pragma unroll
    for (int u = 0; u < 3; ++u) {
        y0 = fmaf(B.w2[0][u], a[u], y0);
        y1 = fmaf(B.w2[1][u], a[u], y1);
        y2 = fmaf(B.w2[2][u], a[u], y2);
    }
    v0 = red16(p * y0);
    v1 = red16(p * y1);
    v2 = red16(p * y2);
}

__device__ __forceinline__ float div_eval(const BlkW& B, float kf, int ii, float t,
                                          float x0, float x1, float x2) {
    float w = fmaf(t, 10.0f, -kf);
    float p = ii ? w : (1.0f - w);
    float s = 0.0f;
    #pragma unroll
    for (int u = 0; u < 3; ++u) {
        float pre = fmaf(B.w1[u][0], x0, fmaf(B.w1[u][1], x1, fmaf(B.w1[u][2], x2, B.b1v[u])));
        float th = fast_tanh(pre);
        s = fmaf(B.g[u], 1.0f - th * th, s);
    }
    return red16(p * s);
}

// One RK4 substep (step = H/4) with K1 passed in; x updated in place.
__device__ __forceinline__ void rk4x(const BlkW& B, float kf, int ii, float t,
                                     float& x0, float& x1, float& x2,
                                     float k10, float k11, float k12) {
    const float s  = H_ * 0.25f;
    const float hs = s * 0.5f;
    float k20, k21, k22, k30, k31, k32, k40, k41, k42;
    v_eval(B, kf, ii, t + hs, fmaf(hs, k10, x0), fmaf(hs, k11, x1), fmaf(hs, k12, x2), k20, k21, k22);
    v_eval(B, kf, ii, t + hs, fmaf(hs, k20, x0), fmaf(hs, k21, x1), fmaf(hs, k22, x2), k30, k31, k32);
    v_eval(B, kf, ii, t + s,  fmaf(s,  k30, x0), fmaf(s,  k31, x1), fmaf(s,  k32, x2), k40, k41, k42);
    const float c = s / 6.0f;
    x0 += c * (k10 + 2.0f * (k20 + k30) + k40);
    x1 += c * (k11 + 2.0f * (k21 + k31) + k41);
    x2 += c * (k12 + 2.0f * (k22 + k32) + k42);
}

__global__ void __launch_bounds__(256)
loss_main_kernel(const float* __restrict__ x,
                 const float* __restrict__ W1, const float* __restrict__ b1,
                 const float* __restrict__ W2, const float* __restrict__ b2,
                 double* __restrict__ ws) {
    int gid  = blockIdx.x * blockDim.x + threadIdx.x;
    int r    = gid >> 4;
    int sub  = gid & 15;      // 16 lanes per sample, aligned within the wave
    int ii   = sub >> 3;      // which of the 2 active basis indices
    int rest = sub & 7;
    int l    = rest & 3;      // block column; l==3 -> idle
    int hh   = rest >> 2;     // hidden half: 0 -> h{0,1,2}, 1 -> h{3,4,pad}
    bool act = (l < 3);

    float X0 = x[r * 3 + 0];
    float X1 = x[r * 3 + 1];
    float X2 = x[r * 3 + 2];

    float lnRo = -0.5f * (3.0f * LOG_2PI + X0 * X0 + X1 * X1 + X2 * X2); // lnrho(x,0,1)
    float loss1p = 0.0f;
    float vA0 = 0.f, vA1 = 0.f, vA2 = 0.f;

    BlkW B;

    #pragma unroll 1
    for (int k = 0; k < N_; ++k) {
        float kf = (float)k;
        float tn = kf * H_;
        load_blk(B, W1, b1, W2, b2, k + ii, l, hh, act);

        if (k == 0) v_eval(B, kf, ii, tn, X0, X1, X2, vA0, vA1, vA2);

        // ---- 4 RK4 substeps, saving intermediate states for the div integrals
        float s00 = X0, s01 = X1, s02 = X2;                      // X0
        rk4x(B, kf, ii, tn, X0, X1, X2, vA0, vA1, vA2);          // -> X1
        float s10 = X0, s11 = X1, s12 = X2;

        float t1 = tn + 0.25f * H_;
        float q0, q1, q2;
        v_eval(B, kf, ii, t1, X0, X1, X2, q0, q1, q2);
        rk4x(B, kf, ii, t1, X0, X1, X2, q0, q1, q2);             // -> X2
        float s20 = X0, s21 = X1, s22 = X2;

        float t2 = tn + 0.5f * H_;
        float vB0, vB1, vB2;
        v_eval(B, kf, ii, t2, X0, X1, X2, vB0, vB1, vB2);
        rk4x(B, kf, ii, t2, X0, X1, X2, vB0, vB1, vB2);          // -> X3
        float s30 = X0, s31 = X1, s32 = X2;

        float t3 = tn + 0.75f * H_;
        v_eval(B, kf, ii, t3, X0, X1, X2, q0, q1, q2);
        rk4x(B, kf, ii, t3, X0, X1, X2, q0, q1, q2);             // -> X4 (in X0..X2)

        float t4 = tn + H_;

        // ---- divergence integrals (two rk4_lnro calls share d2)
        float d0 = div_eval(B, kf, ii, tn, s00, s01, s02);
        float d1 = div_eval(B, kf, ii, t1, s10, s11, s12);
        float d2 = div_eval(B, kf, ii, t2, s20, s21, s22);
        float d3 = div_eval(B, kf, ii, t3, s30, s31, s32);
        float d4 = div_eval(B, kf, ii, t4, X0, X1, X2);
        lnRo += (H_ / 12.0f) * (-d0 - 4.0f * d1 - d2)
              + (H_ / 12.0f) * (-d2 - 4.0f * d3 - d4);

        // ---- loss1 terms: v(X0,tn)=vA, v(X2,tn+H/2)=vB, v(X4,tn+H)=vC (-> next vA)
        float vC0, vC1, vC2;
        v_eval(B, kf, ii, t4, X0, X1, X2, vC0, vC1, vC2);
        loss1p += (vA0 * vA0 + vA1 * vA1 + vA2 * vA2)
                + 4.0f * (vB0 * vB0 + vB1 * vB1 + vB2 * vB2)
                + (vC0 * vC0 + vC1 * vC1 + vC2 * vC2);
        vA0 = vC0; vA1 = vC1; vA2 = vC2;
    }

    // KL term per sample: lnRo - lnrho(X_final, 1, 1)
    float e0 = X0 - 1.0f, e1 = X1 - 1.0f, e2 = X2 - 1.0f;
    float lnr1 = -0.5f * (3.0f * LOG_2PI + e0 * e0 + e1 * e1 + e2 * e2);
    float klp = lnRo - lnr1;

    // per-sample values replicated across 16 lanes -> keep lane 0 of each group
    if ((threadIdx.x & 15) != 0) { loss1p = 0.0f; klp = 0.0f; }
    #pragma unroll
    for (int off = 16; off < 64; off <<= 1) {   // once per kernel: shfl is fine here
        loss1p += __shfl_xor(loss1p, off);
        klp    += __shfl_xor(klp, off);
    }
    // every wave writes its partial unconditionally -> no zero-init kernel needed
    if ((threadIdx.x & 63) == 0) {
        int wid = gid >> 6;
        ws[wid]          = (double)loss1p;
        ws[NWAVES + wid] = (double)klp;
    }
}

__global__ void __launch_bounds__(64)
finalize_kernel(const double* __restrict__ ws, float* __restrict__ out) {
    // single wave: each lane sums NWAVES/64 partials of each accumulator, then reduce
    int lane = threadIdx.x;
    double l1 = 0.0, kl = 0.0;
    #pragma unroll
    for (int j = 0; j < NWAVES / 64; ++j) {
        l1 += ws[lane + j * 64];
        kl += ws[NWAVES + lane + j * 64];
    }
    #pragma unroll
    for (int off = 1; off < 64; off <<= 1) {
        l1 += __shfl_xor(l1, off);
        kl += __shfl_xor(kl, off);
    }
    if (lane == 0) {
        double l1s = (double)H_ / (6.0 * (double)R_) * l1;
        double kls = kl / (double)R_;
        float l1f = (float)l1s;
        float klf = (float)kls;
        out[0] = l1f + klf;   // loss  (loss_F == 0)
        out[1] = l1f;         // loss1
        out[2] = klf;         // loss_KL
        out[3] = 0.0f;        // loss_F
    }
}

extern "C" void kernel_launch(void* const* d_in, const int* in_sizes, int n_in,
                              void* d_out, int out_size, void* d_ws, size_t ws_size,
                              hipStream_t stream) {
    const float* x  = (const float*)d_in[0];
    const float* W1 = (const float*)d_in[1];
    const float* b1 = (const float*)d_in[2];
    const float* W2 = (const float*)d_in[3];
    const float* b2 = (const float*)d_in[4];
    double* ws = (double*)d_ws;   // [0..2047]=loss1 wave partials, [2048..4095]=KL
    float* out = (float*)d_out;

    // 8192 samples x 16 lanes = 131072 threads = 512 blocks x 256 -> 2 waves/SIMD
    loss_main_kernel<<<512, 256, 0, stream>>>(x, W1, b1, W2, b2, ws);
    finalize_kernel<<<1, 64, 0, stream>>>(ws, out);
}

// Round 5
// 100.956 us; speedup vs baseline: 1.0860x; 1.0860x over previous
//
#include <hip/hip_runtime.h>

// Loss_net: neural-ODE loss forward. R=8192 samples, D=3, N=10 RK4 super-steps.
// 16 lanes per sample, 2 unit-tasks per lane: the 30 unit-tasks are
// (basis ii in {k,k+1}) x (l in 0..2) x (h in 0..4). Lanes 0-7 carry ii=0's 15
// tasks (2 per lane, lane 7 has 1 + pad), lanes 8-15 carry ii=1's. 31/32 lane
// utilization (vs 24/32 for the previous l-split). Cross-lane sums via 4-stage
// DPP butterfly (VALU pipe). 131072 threads = 2048 waves = 2 waves/SIMD.

#define R_    8192
#define M_    10
#define L_    3
#define HID_  5
#define D_    3
#define N_    10
#define H_    0.1f
#define LOG_2PI 1.8378770664093453f
#define NWAVES 2048   // 512 blocks x 256 threads / 64

__device__ __forceinline__ float fast_tanh(float x) {
    // tanh(x) = 1 - 2/(exp(2x)+1); exp via hw exp2, rcp via hw rcp (~1e-7 rel err)
    float e = __builtin_amdgcn_exp2f(x * 2.8853900817779268f); // 2*log2(e)*x
    return fmaf(-2.0f, __builtin_amdgcn_rcpf(e + 1.0f), 1.0f);
}

// --- DPP butterfly add over 16 contiguous lanes (all lanes get the sum) ---
// 0xB1 quad_perm xor1, 0x4E quad_perm xor2, 0x141 row_half_mirror (i<->7-i in 8),
// 0x140 row_mirror (i<->15-i in 16). NOTE: 0x142 is ROW_BCAST15, not a mirror.
template<int CTRL>
__device__ __forceinline__ float dpp_addf(float v) {
    int t = __builtin_amdgcn_update_dpp(0, __float_as_int(v), CTRL, 0xF, 0xF, true);
    return v + __int_as_float(t);
}
__device__ __forceinline__ float red16(float v) {
    v = dpp_addf<0xB1>(v);
    v = dpp_addf<0x4E>(v);
    v = dpp_addf<0x141>(v);
    v = dpp_addf<0x140>(v);
    return v;
}

struct BlkW {
    float w1[2][D_];   // my 2 unit-tasks: W1 rows
    float b1v[2];
    float w2[2][D_];   // W2 columns for my units (unit-major)
    float b2v[D_];     // lanes j<3 of each half carry b2 of block (ii, l=j)
    float g[2];        // g[u] = sum_d w2[u][d]*w1[u][d]
};

__device__ __forceinline__ void load_blk(BlkW& B,
                                         const float* __restrict__ W1,
                                         const float* __restrict__ b1,
                                         const float* __restrict__ W2,
                                         const float* __restrict__ b2,
                                         int k, int ii, int j) {
    int ibase = (k + ii) * L_;                  // first block row of my basis
    #pragma unroll
    for (int u = 0; u < 2; ++u) {
        int tau = 2 * j + u;                    // unit-task 0..15
        bool au = (tau < 15);
        int ts  = au ? tau : 0;                 // safe index for the pad task
        int l   = ts / 5;                       // 0..2
        int h   = ts - 5 * l;                   // 0..4
        int blk = ibase + l;
        #pragma unroll
        for (int d = 0; d < D_; ++d) {
            float w1v = W1[blk * (HID_ * D_) + h * D_ + d];
            B.w1[u][d] = au ? w1v : 0.0f;
            float w2v = W2[blk * (D_ * HID_) + d * HID_ + h];
            B.w2[u][d] = au ? w2v : 0.0f;
        }
        float b1x = b1[blk * HID_ + h];
        B.b1v[u] = au ? b1x : 0.0f;
    }
    bool ab2 = (j < 3);
    int blk2 = ibase + (ab2 ? j : 0);
    #pragma unroll
    for (int d = 0; d < D_; ++d) {
        float b2x = b2[blk2 * D_ + d];
        B.b2v[d] = ab2 ? b2x : 0.0f;
    }
    #pragma unroll
    for (int u = 0; u < 2; ++u)
        B.g[u] = B.w2[u][0] * B.w1[u][0] + B.w2[u][1] * B.w1[u][1] + B.w2[u][2] * B.w1[u][2];
}

// v field eval: lane computes its 2-unit partial, then 16-lane DPP reduce.
// All 16 lanes end with the full v vector.
__device__ __forceinline__ void v_eval(const BlkW& B, float kf, int ii, float t,
                                       float x0, float x1, float x2,
                                       float& v0, float& v1, float& v2) {
    float w = fmaf(t, 10.0f, -kf);          // u - k
    float p = ii ? w : (1.0f - w);          // my basis weight
    float pre0 = fmaf(B.w1[0][0], x0, fmaf(B.w1[0][1], x1, fmaf(B.w1[0][2], x2, B.b1v[0])));
    float pre1 = fmaf(B.w1[1][0], x0, fmaf(B.w1[1][1], x1, fmaf(B.w1[1][2], x2, B.b1v[1])));
    float a0 = fast_tanh(pre0);
    float a1 = fast_tanh(pre1);
    // b2 folded as the innermost addend (no extra movs)
    float y0 = fmaf(B.w2[0][0], a0, fmaf(B.w2[1][0], a1, B.b2v[0]));
    float y1 = fmaf(B.w2[0][1], a0, fmaf(B.w2[1][1], a1, B.b2v[1]));
    float y2 = fmaf(B.w2[0][2], a0, fmaf(B.w2[1][2], a1, B.b2v[2]));
    v0 = red16(p * y0);
    v1 = red16(p * y1);
    v2 = red16(p * y2);
}

__device__ __forceinline__ float div_eval(const BlkW& B, float kf, int ii, float t,
                                          float x0, float x1, float x2) {
    float w = fmaf(t, 10.0f, -kf);
    float p = ii ? w : (1.0f - w);
    float pre0 = fmaf(B.w1[0][0], x0, fmaf(B.w1[0][1], x1, fmaf(B.w1[0][2], x2, B.b1v[0])));
    float pre1 = fmaf(B.w1[1][0], x0, fmaf(B.w1[1][1], x1, fmaf(B.w1[1][2], x2, B.b1v[1])));
    float a0 = fast_tanh(pre0);
    float a1 = fast_tanh(pre1);
    float s = B.g[0] * (1.0f - a0 * a0) + B.g[1] * (1.0f - a1 * a1);
    return red16(p * s);
}

// One RK4 substep (step = H/4) with K1 passed in; x updated in place.
__device__ __forceinline__ void rk4x(const BlkW& B, float kf, int ii, float t,
                                     float& x0, float& x1, float& x2,
                                     float k10, float k11, float k12) {
    const float s  = H_ * 0.25f;
    const float hs = s * 0.5f;
    float k20, k21, k22, k30, k31, k32, k40, k41, k42;
    v_eval(B, kf, ii, t + hs, fmaf(hs, k10, x0), fmaf(hs, k11, x1), fmaf(hs, k12, x2), k20, k21, k22);
    v_eval(B, kf, ii, t + hs, fmaf(hs, k20, x0), fmaf(hs, k21, x1), fmaf(hs, k22, x2), k30, k31, k32);
    v_eval(B, kf, ii, t + s,  fmaf(s,  k30, x0), fmaf(s,  k31, x1), fmaf(s,  k32, x2), k40, k41, k42);
    const float c = s / 6.0f;
    x0 += c * (k10 + 2.0f * (k20 + k30) + k40);
    x1 += c * (k11 + 2.0f * (k21 + k31) + k41);
    x2 += c * (k12 + 2.0f * (k22 + k32) + k42);
}

__global__ void __launch_bounds__(256)
loss_main_kernel(const float* __restrict__ x,
                 const float* __restrict__ W1, const float* __restrict__ b1,
                 const float* __restrict__ W2, const float* __restrict__ b2,
                 double* __restrict__ ws) {
    int gid  = blockIdx.x * blockDim.x + threadIdx.x;
    int r    = gid >> 4;
    int sub  = gid & 15;      // 16 lanes per sample, aligned within the wave
    int ii   = sub >> 3;      // which of the 2 active basis indices
    int j    = sub & 7;       // lane within half: unit-tasks {2j, 2j+1}

    float X0 = x[r * 3 + 0];
    float X1 = x[r * 3 + 1];
    float X2 = x[r * 3 + 2];

    float lnRo = -0.5f * (3.0f * LOG_2PI + X0 * X0 + X1 * X1 + X2 * X2); // lnrho(x,0,1)
    float loss1p = 0.0f;
    float vA0 = 0.f, vA1 = 0.f, vA2 = 0.f;

    BlkW B;

    #pragma unroll 1
    for (int k = 0; k < N_; ++k) {
        float kf = (float)k;
        float tn = kf * H_;
        load_blk(B, W1, b1, W2, b2, k, ii, j);

        if (k == 0) v_eval(B, kf, ii, tn, X0, X1, X2, vA0, vA1, vA2);

        // ---- 4 RK4 substeps, saving intermediate states for the div integrals
        float s00 = X0, s01 = X1, s02 = X2;                      // X0
        rk4x(B, kf, ii, tn, X0, X1, X2, vA0, vA1, vA2);          // -> X1
        float s10 = X0, s11 = X1, s12 = X2;

        float t1 = tn + 0.25f * H_;
        float q0, q1, q2;
        v_eval(B, kf, ii, t1, X0, X1, X2, q0, q1, q2);
        rk4x(B, kf, ii, t1, X0, X1, X2, q0, q1, q2);             // -> X2
        float s20 = X0, s21 = X1, s22 = X2;

        float t2 = tn + 0.5f * H_;
        float vB0, vB1, vB2;
        v_eval(B, kf, ii, t2, X0, X1, X2, vB0, vB1, vB2);
        rk4x(B, kf, ii, t2, X0, X1, X2, vB0, vB1, vB2);          // -> X3
        float s30 = X0, s31 = X1, s32 = X2;

        float t3 = tn + 0.75f * H_;
        v_eval(B, kf, ii, t3, X0, X1, X2, q0, q1, q2);
        rk4x(B, kf, ii, t3, X0, X1, X2, q0, q1, q2);             // -> X4 (in X0..X2)

        float t4 = tn + H_;

        // ---- divergence integrals (two rk4_lnro calls share d2)
        float d0 = div_eval(B, kf, ii, tn, s00, s01, s02);
        float d1 = div_eval(B, kf, ii, t1, s10, s11, s12);
        float d2 = div_eval(B, kf, ii, t2, s20, s21, s22);
        float d3 = div_eval(B, kf, ii, t3, s30, s31, s32);
        float d4 = div_eval(B, kf, ii, t4, X0, X1, X2);
        lnRo += (H_ / 12.0f) * (-d0 - 4.0f * d1 - d2)
              + (H_ / 12.0f) * (-d2 - 4.0f * d3 - d4);

        // ---- loss1 terms: v(X0,tn)=vA, v(X2,tn+H/2)=vB, v(X4,tn+H)=vC (-> next vA)
        float vC0, vC1, vC2;
        v_eval(B, kf, ii, t4, X0, X1, X2, vC0, vC1, vC2);
        loss1p += (vA0 * vA0 + vA1 * vA1 + vA2 * vA2)
                + 4.0f * (vB0 * vB0 + vB1 * vB1 + vB2 * vB2)
                + (vC0 * vC0 + vC1 * vC1 + vC2 * vC2);
        vA0 = vC0; vA1 = vC1; vA2 = vC2;
    }

    // KL term per sample: lnRo - lnrho(X_final, 1, 1)
    float e0 = X0 - 1.0f, e1 = X1 - 1.0f, e2 = X2 - 1.0f;
    float lnr1 = -0.5f * (3.0f * LOG_2PI + e0 * e0 + e1 * e1 + e2 * e2);
    float klp = lnRo - lnr1;

    // per-sample values replicated across 16 lanes -> keep lane 0 of each group
    if ((threadIdx.x & 15) != 0) { loss1p = 0.0f; klp = 0.0f; }
    #pragma unroll
    for (int off = 16; off < 64; off <<= 1) {   // once per kernel: shfl is fine here
        loss1p += __shfl_xor(loss1p, off);
        klp    += __shfl_xor(klp, off);
    }
    // every wave writes its partial unconditionally -> no zero-init kernel needed
    if ((threadIdx.x & 63) == 0) {
        int wid = gid >> 6;
        ws[wid]          = (double)loss1p;
        ws[NWAVES + wid] = (double)klp;
    }
}

__global__ void __launch_bounds__(64)
finalize_kernel(const double* __restrict__ ws, float* __restrict__ out) {
    // single wave: each lane sums NWAVES/64 partials of each accumulator, then reduce
    int lane = threadIdx.x;
    double l1 = 0.0, kl = 0.0;
    #pragma unroll
    for (int j = 0; j < NWAVES / 64; ++j) {
        l1 += ws[lane + j * 64];
        kl += ws[NWAVES + lane + j * 64];
    }
    #pragma unroll
    for (int off = 1; off < 64; off <<= 1) {
        l1 += __shfl_xor(l1, off);
        kl += __shfl_xor(kl, off);
    }
    if (lane == 0) {
        double l1s = (double)H_ / (6.0 * (double)R_) * l1;
        double kls = kl / (double)R_;
        float l1f = (float)l1s;
        float klf = (float)kls;
        out[0] = l1f + klf;   // loss  (loss_F == 0)
        out[1] = l1f;         // loss1
        out[2] = klf;         // loss_KL
        out[3] = 0.0f;        // loss_F
    }
}

extern "C" void kernel_launch(void* const* d_in, const int* in_sizes, int n_in,
                              void* d_out, int out_size, void* d_ws, size_t ws_size,
                              hipStream_t stream) {
    const float* x  = (const float*)d_in[0];
    const float* W1 = (const float*)d_in[1];
    const float* b1 = (const float*)d_in[2];
    const float* W2 = (const float*)d_in[3];
    const float* b2 = (const float*)d_in[4];
    double* ws = (double*)d_ws;   // [0..2047]=loss1 wave partials, [2048..4095]=KL
    float* out = (float*)d_out;

    // 8192 samples x 16 lanes = 131072 threads = 512 blocks x 256 -> 2 waves/SIMD
    loss_main_kernel<<<512, 256, 0, stream>>>(x, W1, b1, W2, b2, ws);
    finalize_kernel<<<1, 64, 0, stream>>>(ws, out);
}